// Round 8
// baseline (922.897 us; speedup 1.0000x reference)
//
#include <hip/hip_runtime.h>
#include <math.h>

#define B 256
#define LC 400
#define LQ 50
#define D 128
#define CT 64

// ---------------------------------------------------------------------------
// K0: zero the per-batch tile counters (live in out_res[0..255], overwritten
// by K3 later). Runs each graph replay before K1.
// ---------------------------------------------------------------------------
__global__ void k_zero(int* __restrict__ cnt)
{
    cnt[threadIdx.x] = 0;
}

// ---------------------------------------------------------------------------
// K1: scores tile GEMM + ROW softmax fused (r7 structure, LDS unioned) +
// last-block-per-batch COLUMN softmax finalize + T = S_T @ xc.
// Grid (7, B), 256 thr, 80.4KB LDS union -> 2 blocks/CU.
// After a block writes its S_bar / raw-S^T tile: threadfence + atomicAdd on
// cnt[b]; the 7th block for batch b reads the (L2-hot) raw S^T from global,
// finalizes the column softmax, writes final S_T, and computes T[b] --
// overlapped with other batches' score tiles.
// ---------------------------------------------------------------------------
__global__ __launch_bounds__(256, 2) void k_scores_fused(
    const float* __restrict__ xc_g, const float* __restrict__ xq_g,
    const float* __restrict__ W0, const float* __restrict__ W1,
    const float* __restrict__ W2, const int* __restrict__ cont_len,
    const int* __restrict__ ques_len,
    float* __restrict__ S_bar, float* __restrict__ S_Traw,
    float* __restrict__ T, int* __restrict__ cnt)
{
    __shared__ __align__(16) float smem[20104];   // 80.4 KB union
    __shared__ int isLast;
    float* xq   = smem;            // 56*132 = 7392
    float* xc   = smem + 7392;     // 64*132 = 8448
    float* sS   = smem + 15840;    // 64*51  = 3264
    float* w    = smem + 19104;    // 384
    float* sq   = smem + 19488;    // 56
    float* sc   = smem + 19544;    // 64
    float* rowm = smem + 19608;    // 64
    float* rowi = smem + 19672;    // 64  (end 19736)

    const int b = blockIdx.y;
    const int c0 = blockIdx.x * CT;
    const int t = threadIdx.x;
    const int nc = min(CT, LC - c0);
    const int qlen = ques_len[b];

    // ---- stage xq (56 rows, tail zeroed), xc tile, weights ----
    const float4* xq4g = (const float4*)(xq_g + (size_t)b * LQ * D);
    for (int i = t; i < 56 * 32; i += 256) {
        float4 v = (i < LQ * 32) ? xq4g[i] : make_float4(0.f, 0.f, 0.f, 0.f);
        ((float4*)xq)[(i >> 5) * 33 + (i & 31)] = v;
    }
    const float4* xc4g = (const float4*)(xc_g + (size_t)(b * LC + c0) * D);
    for (int i = t; i < nc * 32; i += 256)
        ((float4*)xc)[(i >> 5) * 33 + (i & 31)] = xc4g[i];
    if (t < D) { w[t] = W0[t]; w[D + t] = W1[t]; w[2 * D + t] = W2[t]; }
    __syncthreads();

    // ---- bias terms from raw xq / xc (concurrent) ----
    if (t < LQ) {
        const float4* r = (const float4*)(xq + t * 132);
        const float4* wv = (const float4*)(w + D);
        float4 a = {0.f, 0.f, 0.f, 0.f};
#pragma unroll
        for (int d = 0; d < 32; ++d) {
            float4 u = r[d], v = wv[d];
            a.x += u.x * v.x; a.y += u.y * v.y; a.z += u.z * v.z; a.w += u.w * v.w;
        }
        sq[t] = a.x + a.y + a.z + a.w;
    } else if (t >= 64 && t < 128) {
        const int c = t - 64;
        if (c < nc) {
            const float4* r = (const float4*)(xc + c * 132);
            const float4* wv = (const float4*)w;
            float4 a = {0.f, 0.f, 0.f, 0.f};
#pragma unroll
            for (int d = 0; d < 32; ++d) {
                float4 u = r[d], v = wv[d];
                a.x += u.x * v.x; a.y += u.y * v.y; a.z += u.z * v.z; a.w += u.w * v.w;
            }
            sc[c] = a.x + a.y + a.z + a.w;
        }
    }
    __syncthreads();
    // ---- scale xq rows by W2 in place ----
    for (int i = t; i < LQ * D; i += 256)
        xq[(i >> 7) * 132 + (i & 127)] *= w[2 * D + (i & 127)];
    __syncthreads();

    // ---- GEMM with K-split: (cg,qg) tile = c = cg+16k (k<4), q = qg*7+j ----
    const int qg = t & 7;
    const int cg = (t >> 3) & 15;
    const int half = t >> 7;
    const int d0 = half * 16;

    float acc[4][7];
#pragma unroll
    for (int k = 0; k < 4; ++k)
#pragma unroll
        for (int j = 0; j < 7; ++j) acc[k][j] = 0.f;

    {
        const float4* xc4 = (const float4*)xc;
        const float4* xq4 = (const float4*)xq;
#pragma unroll 4
        for (int dd = 0; dd < 16; ++dd) {
            const int d4 = d0 + dd;
            const float4 a0 = xc4[(cg + 0)  * 33 + d4];
            const float4 a1 = xc4[(cg + 16) * 33 + d4];
            const float4 a2 = xc4[(cg + 32) * 33 + d4];
            const float4 a3 = xc4[(cg + 48) * 33 + d4];
#pragma unroll
            for (int j = 0; j < 7; ++j) {
                const float4 bq = xq4[(qg * 7 + j) * 33 + d4];
                acc[0][j] += a0.x*bq.x + a0.y*bq.y + a0.z*bq.z + a0.w*bq.w;
                acc[1][j] += a1.x*bq.x + a1.y*bq.y + a1.z*bq.z + a1.w*bq.w;
                acc[2][j] += a2.x*bq.x + a2.y*bq.y + a2.z*bq.z + a2.w*bq.w;
                acc[3][j] += a3.x*bq.x + a3.y*bq.y + a3.z*bq.z + a3.w*bq.w;
            }
        }
    }
    if (half) {
#pragma unroll
        for (int k = 0; k < 4; ++k) {
            const int c = cg + 16 * k;
            if (c < nc) {
#pragma unroll
                for (int j = 0; j < 7; ++j) {
                    const int q = qg * 7 + j;
                    if (q < LQ) sS[c * 51 + q] = acc[k][j];
                }
            }
        }
    }
    __syncthreads();
    if (!half) {
#pragma unroll
        for (int k = 0; k < 4; ++k) {
            const int c = cg + 16 * k;
            if (c < nc) {
                const float scc = sc[c];
#pragma unroll
                for (int j = 0; j < 7; ++j) {
                    const int q = qg * 7 + j;
                    if (q < LQ)
                        sS[c * 51 + q] = acc[k][j] + sS[c * 51 + q] + scc + sq[q];
                }
            }
        }
    }
    __syncthreads();

    // ---- row softmax stats, 4 threads/row (chain 50 -> 13) ----
    float* redr = w;                   // alias dead w[]
    {
        const int r = t & 63, seg = t >> 6;
        const int qb = seg * 13;
        const int qe = min(qb + 13, qlen);
        float m = -INFINITY;
        for (int q = qb; q < qe; ++q) m = fmaxf(m, sS[r * 51 + q]);
        redr[t] = m;
    }
    __syncthreads();
    if (t < 64)
        rowm[t] = fmaxf(fmaxf(redr[t], redr[64 + t]),
                        fmaxf(redr[128 + t], redr[192 + t]));
    __syncthreads();
    {
        const int r = t & 63, seg = t >> 6;
        const int qb = seg * 13;
        const int qe = min(qb + 13, qlen);
        const float m = rowm[r];
        float s = 0.f;
        for (int q = qb; q < qe; ++q) s += __expf(sS[r * 51 + q] - m);
        redr[t] = s;
    }
    __syncthreads();
    if (t < 64)
        rowi[t] = 1.f / (redr[t] + redr[64 + t] + redr[128 + t] + redr[192 + t]);
    __syncthreads();

    // ---- S_bar write (final, coalesced) ----
    float* Sb = S_bar + (size_t)(b * LC + c0) * LQ;
    for (int i = t; i < nc * LQ; i += 256) {
        const int c = i / LQ, q = i - c * LQ;
        Sb[i] = (q < qlen) ? __expf(sS[c * 51 + q] - rowm[c]) * rowi[c] : 0.f;
    }
    // ---- raw S^T write (256B runs per q-row) ----
    float* STb = S_Traw + (size_t)b * LQ * LC + c0;
    for (int i = t; i < LQ * 64; i += 256) {
        const int q = i >> 6, c = i & 63;
        if (c < nc) STb[q * LC + c] = sS[c * 51 + q];
    }

    // ==== last-block-per-batch: column softmax finalize + T GEMM ====
    __syncthreads();                       // all stores of this block issued+drained
    if (t == 0) {
        __threadfence();                   // release: flush to coherence point
        isLast = (atomicAdd(&cnt[b], 1) == 6);
    }
    __syncthreads();
    if (!isLast) return;
    __threadfence();                       // acquire: invalidate stale cache

    float* sT     = smem;                  // 50*400 (aliases everything)
    float* colmax = smem + 20000;          // 50
    float* colinv = smem + 20050;          // 50
    float* redf   = smem;                  // 250 (used before sT is staged)
    const int clen = cont_len[b];
    float* STf = S_Traw + (size_t)b * LQ * LC;

    // col stats from global (L2/L3-hot), 5 chunks of 80 per q
    if (t < 250) {
        const int q = t % 50, g = t / 50;
        const int cb = g * 80, ce = min(cb + 80, clen);
        float m = -INFINITY;
        for (int c = cb; c < ce; ++c) m = fmaxf(m, STf[q * LC + c]);
        redf[t] = m;
    }
    __syncthreads();
    if (t < LQ) {
        float m = redf[t];
#pragma unroll
        for (int k = 1; k < 5; ++k) m = fmaxf(m, redf[k * 50 + t]);
        colmax[t] = m;
    }
    __syncthreads();
    if (t < 250) {
        const int q = t % 50, g = t / 50;
        const int cb = g * 80, ce = min(cb + 80, clen);
        float s = 0.f;
        const float cm = colmax[q];
        for (int c = cb; c < ce; ++c) s += __expf(STf[q * LC + c] - cm);
        redf[t] = s;
    }
    __syncthreads();
    if (t < LQ) {
        float s = redf[t];
#pragma unroll
        for (int k = 1; k < 5; ++k) s += redf[k * 50 + t];
        colinv[t] = 1.f / s;
    }
    __syncthreads();

    // normalize: write final S_T (global, in place) + stage into LDS
    for (int i = t; i < LQ * LC; i += 256) {
        const int q = i / LC, c = i - q * LC;
        const float v = (c < clen) ? __expf(STf[i] - colmax[q]) * colinv[q] : 0.f;
        sT[q * 400 + c] = v;
        STf[i] = v;
    }
    __syncthreads();

    // T GEMM: T[b] = S_T @ xc. d4 = t&31; qg2 = t>>5 owns q = qg2*7+j
    const int d4f = t & 31, qg2 = t >> 5;
    float4 accf[7];
#pragma unroll
    for (int j = 0; j < 7; ++j) accf[j] = make_float4(0.f, 0.f, 0.f, 0.f);

    const float4* xcv = (const float4*)xc_g + (size_t)b * LC * 32 + d4f;
    for (int c = 0; c < LC; c += 4) {
        const float4 x0 = xcv[(c + 0) * 32];
        const float4 x1 = xcv[(c + 1) * 32];
        const float4 x2 = xcv[(c + 2) * 32];
        const float4 x3 = xcv[(c + 3) * 32];
#pragma unroll
        for (int j = 0; j < 7; ++j) {
            const int q = qg2 * 7 + j;
            if (q < LQ) {
                const float4 wv = ((const float4*)(sT + q * 400))[c >> 2];
                accf[j].x += wv.x * x0.x + wv.y * x1.x + wv.z * x2.x + wv.w * x3.x;
                accf[j].y += wv.x * x0.y + wv.y * x1.y + wv.z * x2.y + wv.w * x3.y;
                accf[j].z += wv.x * x0.z + wv.y * x1.z + wv.z * x2.z + wv.w * x3.z;
                accf[j].w += wv.x * x0.w + wv.y * x1.w + wv.z * x2.w + wv.w * x3.w;
            }
        }
    }
    float4* Tb = (float4*)T + (size_t)b * LQ * 32 + d4f;
#pragma unroll
    for (int j = 0; j < 7; ++j) {
        const int q = qg2 * 7 + j;
        if (q < LQ) Tb[q * 32] = accf[j];
    }
}

// ---------------------------------------------------------------------------
// K3: out[b,c,:] = [xc, c2q, xc*c2q, xc*q2c]. Grid (7 c-tiles, B), block 256,
// 2 blocks/CU. [byte-identical to round-7 measured 436.6]
// ---------------------------------------------------------------------------
#define FMA4(A, s, V) { A.x += (s) * V.x; A.y += (s) * V.y; A.z += (s) * V.z; A.w += (s) * V.w; }

__global__ __launch_bounds__(256, 2) void k_out(
    const float* __restrict__ S_bar, const float* __restrict__ xq_g,
    const float* __restrict__ Tm, const float* __restrict__ xc_g,
    float* __restrict__ out)
{
    __shared__ __align__(16) float xqL[LQ * 132];
    __shared__ __align__(16) float TL[LQ * 132];
    __shared__ __align__(16) float sbT[LQ * 68];   // [q][c-tile], 68 fl = 17x16B

    const int b = blockIdx.y;
    const int c0 = blockIdx.x * CT;
    const int t = threadIdx.x;
    const int nc = min(CT, LC - c0);

    const float4* xq4g = (const float4*)(xq_g + (size_t)b * LQ * D);
    const float4* T4g  = (const float4*)(Tm + (size_t)b * LQ * D);
    for (int i = t; i < LQ * 32; i += 256) {
        const int row = i >> 5, col = i & 31;
        ((float4*)xqL)[row * 33 + col] = xq4g[i];
        ((float4*)TL)[row * 33 + col]  = T4g[i];
    }
    const float* sb_g = S_bar + (size_t)(b * LC + c0) * LQ;
    for (int i = t; i < CT * LQ; i += 256) {
        const int c = i / LQ, q = i - c * LQ;
        sbT[q * 68 + c] = (c < nc) ? sb_g[i] : 0.f;
    }

    const int d4 = t & 31, cg = t >> 5;   // cg 0..7 owns 8 c rows
    const int cbase = cg * 8;

    // prefetch epilogue xc rows (consumed after GEMM; HBM latency hidden)
    const float4* xcv = (const float4*)xc_g;
    float4 xcr[8];
#pragma unroll
    for (int i = 0; i < 8; ++i) {
        int row = b * LC + c0 + cbase + i;
        row = min(row, B * LC - 1);
        xcr[i] = xcv[(size_t)row * 32 + d4];
    }
    __syncthreads();

    float4 c2q[8], q2c[8];
#pragma unroll
    for (int i = 0; i < 8; ++i) {
        c2q[i] = make_float4(0.f, 0.f, 0.f, 0.f);
        q2c[i] = make_float4(0.f, 0.f, 0.f, 0.f);
    }
    const float4* xq4 = (const float4*)xqL;
    const float4* T4  = (const float4*)TL;
    const float4* sb4 = (const float4*)sbT;
    const int cb2 = cg * 2;
    for (int qq = 0; qq < LQ; ++qq) {
        const float4 xv = xq4[qq * 33 + d4];
        const float4 tv = T4[qq * 33 + d4];
        const float4 s0 = sb4[qq * 17 + cb2];
        const float4 s1 = sb4[qq * 17 + cb2 + 1];
        FMA4(c2q[0], s0.x, xv); FMA4(q2c[0], s0.x, tv);
        FMA4(c2q[1], s0.y, xv); FMA4(q2c[1], s0.y, tv);
        FMA4(c2q[2], s0.z, xv); FMA4(q2c[2], s0.z, tv);
        FMA4(c2q[3], s0.w, xv); FMA4(q2c[3], s0.w, tv);
        FMA4(c2q[4], s1.x, xv); FMA4(q2c[4], s1.x, tv);
        FMA4(c2q[5], s1.y, xv); FMA4(q2c[5], s1.y, tv);
        FMA4(c2q[6], s1.z, xv); FMA4(q2c[6], s1.z, tv);
        FMA4(c2q[7], s1.w, xv); FMA4(q2c[7], s1.w, tv);
    }

    float4* out4 = (float4*)out;
#pragma unroll
    for (int i = 0; i < 8; ++i) {
        const int c = cbase + i;
        if (c < nc) {
            const int row = b * LC + c0 + c;
            const float4 xc = xcr[i];
            float4* o = out4 + (size_t)row * 128 + d4;
            o[0] = xc;
            o[32] = c2q[i];
            o[64] = make_float4(xc.x * c2q[i].x, xc.y * c2q[i].y,
                                xc.z * c2q[i].z, xc.w * c2q[i].w);
            o[96] = make_float4(xc.x * q2c[i].x, xc.y * q2c[i].y,
                                xc.z * q2c[i].z, xc.w * q2c[i].w);
        }
    }
}

// ---------------------------------------------------------------------------
extern "C" void kernel_launch(void* const* d_in, const int* in_sizes, int n_in,
                              void* d_out, int out_size, void* d_ws, size_t ws_size,
                              hipStream_t stream)
{
    (void)in_sizes; (void)n_in; (void)out_size; (void)ws_size;
    const float* x_cont = (const float*)d_in[0];
    const float* x_ques = (const float*)d_in[1];
    const float* W0 = (const float*)d_in[2];
    const float* W1 = (const float*)d_in[3];
    const float* W2 = (const float*)d_in[4];
    const int* cont_len = (const int*)d_in[5];
    const int* ques_len = (const int*)d_in[6];

    float* out = (float*)d_out;
    float* out_res  = out;                                  // B*LC*4D
    float* out_Sbar = out + (size_t)B * LC * 4 * D;         // B*LC*LQ
    float* out_ST   = out_Sbar + (size_t)B * LC * LQ;       // B*LQ*LC
    float* Tws = (float*)d_ws;                              // B*LQ*D floats
    int* cnt = (int*)out_res;      // counters: overwritten by k_out later

    k_zero<<<1, 256, 0, stream>>>(cnt);
    k_scores_fused<<<dim3(7, B), 256, 0, stream>>>(x_cont, x_ques, W0, W1, W2,
                                                   cont_len, ques_len,
                                                   out_Sbar, out_ST, Tws, cnt);
    k_out<<<dim3(7, B), 256, 0, stream>>>(out_Sbar, x_ques, Tws, x_cont, out_res);
}

// Round 9
// 433.314 us; speedup vs baseline: 2.1299x; 2.1299x over previous
//
#include <hip/hip_runtime.h>
#include <math.h>

#define B 256
#define LC 400
#define LQ 50
#define D 128
#define CT 64

// ---------------------------------------------------------------------------
// K1: scores tile GEMM + ROW softmax fused. Grid (7, B), 256 thr, ~78KB LDS
// (2 blocks/CU, 8 waves). GEMM: 4c x 7q x half-K on ALL 256 threads
// (K-split). Row-softmax stats chunked 4 threads/row (chain 50 -> 13;
// reduction scratch aliases dead w[] region). Writes S_bar (final) + raw S^T.
// [round-7 measured 436.6 us]
// ---------------------------------------------------------------------------
__global__ __launch_bounds__(256, 2) void k_scores_rowsm(
    const float* __restrict__ xc_g, const float* __restrict__ xq_g,
    const float* __restrict__ W0, const float* __restrict__ W1,
    const float* __restrict__ W2, const int* __restrict__ ques_len,
    float* __restrict__ S_bar, float* __restrict__ S_Traw)
{
    __shared__ __align__(16) float xq[56 * 132];   // rows 50..55 zeroed
    __shared__ __align__(16) float xc[CT * 132];
    __shared__ float w[3 * D];                     // dead after scale phase
    __shared__ float sq[56], sc[CT];
    __shared__ float sS[CT * 51];
    __shared__ float rowm[CT], rowi[CT];

    const int b = blockIdx.y;
    const int c0 = blockIdx.x * CT;
    const int t = threadIdx.x;
    const int nc = min(CT, LC - c0);
    const int qlen = ques_len[b];

    // ---- stage xq (56 rows, tail zeroed), xc tile, weights ----
    const float4* xq4g = (const float4*)(xq_g + (size_t)b * LQ * D);
    for (int i = t; i < 56 * 32; i += 256) {
        float4 v = (i < LQ * 32) ? xq4g[i] : make_float4(0.f, 0.f, 0.f, 0.f);
        ((float4*)xq)[(i >> 5) * 33 + (i & 31)] = v;
    }
    const float4* xc4g = (const float4*)(xc_g + (size_t)(b * LC + c0) * D);
    for (int i = t; i < nc * 32; i += 256)
        ((float4*)xc)[(i >> 5) * 33 + (i & 31)] = xc4g[i];
    if (t < D) { w[t] = W0[t]; w[D + t] = W1[t]; w[2 * D + t] = W2[t]; }
    __syncthreads();

    // ---- bias terms from raw xq / xc (concurrent) ----
    if (t < LQ) {
        const float4* r = (const float4*)(xq + t * 132);
        const float4* wv = (const float4*)(w + D);
        float4 a = {0.f, 0.f, 0.f, 0.f};
#pragma unroll
        for (int d = 0; d < 32; ++d) {
            float4 u = r[d], v = wv[d];
            a.x += u.x * v.x; a.y += u.y * v.y; a.z += u.z * v.z; a.w += u.w * v.w;
        }
        sq[t] = a.x + a.y + a.z + a.w;
    } else if (t >= 64 && t < 128) {
        const int c = t - 64;
        if (c < nc) {
            const float4* r = (const float4*)(xc + c * 132);
            const float4* wv = (const float4*)w;
            float4 a = {0.f, 0.f, 0.f, 0.f};
#pragma unroll
            for (int d = 0; d < 32; ++d) {
                float4 u = r[d], v = wv[d];
                a.x += u.x * v.x; a.y += u.y * v.y; a.z += u.z * v.z; a.w += u.w * v.w;
            }
            sc[c] = a.x + a.y + a.z + a.w;
        }
    }
    __syncthreads();
    // ---- scale xq rows by W2 in place (s_f = xc . (W2*xq)) ----
    for (int i = t; i < LQ * D; i += 256)
        xq[(i >> 7) * 132 + (i & 127)] *= w[2 * D + (i & 127)];
    __syncthreads();

    // ---- GEMM with K-split: (cg,qg) tile = c = cg+16k (k<4), q = qg*7+j ----
    const int qg = t & 7;
    const int cg = (t >> 3) & 15;
    const int half = t >> 7;           // 0: d4 in [0,16), 1: d4 in [16,32)
    const int d0 = half * 16;

    float acc[4][7];
#pragma unroll
    for (int k = 0; k < 4; ++k)
#pragma unroll
        for (int j = 0; j < 7; ++j) acc[k][j] = 0.f;

    {
        const float4* xc4 = (const float4*)xc;
        const float4* xq4 = (const float4*)xq;
#pragma unroll 4
        for (int dd = 0; dd < 16; ++dd) {
            const int d4 = d0 + dd;
            const float4 a0 = xc4[(cg + 0)  * 33 + d4];
            const float4 a1 = xc4[(cg + 16) * 33 + d4];
            const float4 a2 = xc4[(cg + 32) * 33 + d4];
            const float4 a3 = xc4[(cg + 48) * 33 + d4];
#pragma unroll
            for (int j = 0; j < 7; ++j) {
                const float4 bq = xq4[(qg * 7 + j) * 33 + d4];
                acc[0][j] += a0.x*bq.x + a0.y*bq.y + a0.z*bq.z + a0.w*bq.w;
                acc[1][j] += a1.x*bq.x + a1.y*bq.y + a1.z*bq.z + a1.w*bq.w;
                acc[2][j] += a2.x*bq.x + a2.y*bq.y + a2.z*bq.z + a2.w*bq.w;
                acc[3][j] += a3.x*bq.x + a3.y*bq.y + a3.z*bq.z + a3.w*bq.w;
            }
        }
    }
    // hi half deposits partials
    if (half) {
#pragma unroll
        for (int k = 0; k < 4; ++k) {
            const int c = cg + 16 * k;
            if (c < nc) {
#pragma unroll
                for (int j = 0; j < 7; ++j) {
                    const int q = qg * 7 + j;
                    if (q < LQ) sS[c * 51 + q] = acc[k][j];
                }
            }
        }
    }
    __syncthreads();
    // lo half combines partial + biases
    if (!half) {
#pragma unroll
        for (int k = 0; k < 4; ++k) {
            const int c = cg + 16 * k;
            if (c < nc) {
                const float scc = sc[c];
#pragma unroll
                for (int j = 0; j < 7; ++j) {
                    const int q = qg * 7 + j;
                    if (q < LQ)
                        sS[c * 51 + q] = acc[k][j] + sS[c * 51 + q] + scc + sq[q];
                }
            }
        }
    }
    __syncthreads();

    // ---- row softmax stats, 4 threads/row (chain 50 -> 13) ----
    float* redr = w;                   // alias dead w[] (384 floats >= 256)
    {
        const int r = t & 63, seg = t >> 6;
        const int qb = seg * 13;
        const int qe = min(qb + 13, qlen);
        float m = -INFINITY;
        for (int q = qb; q < qe; ++q) m = fmaxf(m, sS[r * 51 + q]);
        redr[t] = m;
    }
    __syncthreads();
    if (t < 64)
        rowm[t] = fmaxf(fmaxf(redr[t], redr[64 + t]),
                        fmaxf(redr[128 + t], redr[192 + t]));
    __syncthreads();
    {
        const int r = t & 63, seg = t >> 6;
        const int qb = seg * 13;
        const int qe = min(qb + 13, qlen);
        const float m = rowm[r];
        float s = 0.f;
        for (int q = qb; q < qe; ++q) s += __expf(sS[r * 51 + q] - m);
        redr[t] = s;
    }
    __syncthreads();
    if (t < 64)
        rowi[t] = 1.f / (redr[t] + redr[64 + t] + redr[128 + t] + redr[192 + t]);
    __syncthreads();

    // ---- S_bar write (final, coalesced) ----
    float* Sb = S_bar + (size_t)(b * LC + c0) * LQ;
    for (int i = t; i < nc * LQ; i += 256) {
        const int c = i / LQ, q = i - c * LQ;
        Sb[i] = (q < qlen) ? __expf(sS[c * 51 + q] - rowm[c]) * rowi[c] : 0.f;
    }
    // ---- raw S^T write (256B runs per q-row) ----
    float* STb = S_Traw + (size_t)b * LQ * LC + c0;
    for (int i = t; i < LQ * 64; i += 256) {
        const int q = i >> 6, c = i & 63;
        if (c < nc) STb[q * LC + c] = sS[c * 51 + q];
    }
}

// ---------------------------------------------------------------------------
// K2: COLUMN softmax (over c, mask cont_len) on raw S^T staged in LDS, write
// final S_T out, then T[b] = S_T[b] @ x_cont[b]. One block (512 thr) per b
// (no q-split: splitting duplicates the 52MB xc stream, measured +17us).
// Col stats chunked 10 threads/col (chain 80 -> 40).
// [round-7 measured 436.6 us]
// ---------------------------------------------------------------------------
__global__ __launch_bounds__(512) void k_colsm_qc(
    float* __restrict__ S_T, const float* __restrict__ xc_g,
    const int* __restrict__ cont_len, float* __restrict__ T)
{
    __shared__ __align__(16) float sT[56 * 404];   // rows padded: 404 fl = 101x16B
    __shared__ float red[512];
    __shared__ float colmax[LQ], colinv[LQ];

    const int b = blockIdx.x;
    const int t = threadIdx.x;
    const int clen = cont_len[b];
    float* STb = S_T + (size_t)b * LQ * LC;

    // stage raw S^T (float4)
    const float4* STb4 = (const float4*)STb;
    float4* sTw = (float4*)sT;
    for (int i = t; i < LQ * 100; i += 512)
        sTw[(i / 100) * 101 + (i % 100)] = STb4[i];
    __syncthreads();

    // col stats: 10 chunks of 40 c per q-row (500 threads)
    const int qr = t / 10, g = t - qr * 10;
    if (t < 500) {
        const int cb = g * 40, ce = min(cb + 40, clen);
        float m = -INFINITY;
        for (int c = cb; c < ce; ++c) m = fmaxf(m, sT[qr * 404 + c]);
        red[t] = m;
    }
    __syncthreads();
    if (t < LQ) {
        float m = red[t * 10];
#pragma unroll
        for (int k = 1; k < 10; ++k) m = fmaxf(m, red[t * 10 + k]);
        colmax[t] = m;
    }
    __syncthreads();
    if (t < 500) {
        const int cb = g * 40, ce = min(cb + 40, clen);
        float s = 0.f;
        const float cm = colmax[qr];
        for (int c = cb; c < ce; ++c) s += __expf(sT[qr * 404 + c] - cm);
        red[t] = s;
    }
    __syncthreads();
    if (t < LQ) {
        float s = red[t * 10];
#pragma unroll
        for (int k = 1; k < 10; ++k) s += red[t * 10 + k];
        colinv[t] = 1.f / s;
    }
    __syncthreads();

    // normalize in LDS + write final S_T (coalesced, in place)
    for (int i = t; i < LQ * LC; i += 512) {
        const int q = i / LC, c = i - q * LC;
        const float v = (c < clen) ? __expf(sT[q * 404 + c] - colmax[q]) * colinv[q] : 0.f;
        sT[q * 404 + c] = v;
        STb[i] = v;
    }
    __syncthreads();

    // GEMM: T = S_T @ xc. d4 = t&31, qg = t>>5 owns q = qg*4+j
    const int d4 = t & 31, qg = t >> 5;
    const int qb = qg * 4;
    float4 acc[4];
#pragma unroll
    for (int j = 0; j < 4; ++j) acc[j] = make_float4(0.f, 0.f, 0.f, 0.f);

    const float4* xcv = (const float4*)xc_g + (size_t)b * LC * 32 + d4;
    const float4* sT4 = (const float4*)sT;
    for (int c = 0; c < LC; c += 4) {
        const float4 x0 = xcv[(c + 0) * 32];
        const float4 x1 = xcv[(c + 1) * 32];
        const float4 x2 = xcv[(c + 2) * 32];
        const float4 x3 = xcv[(c + 3) * 32];
#pragma unroll
        for (int j = 0; j < 4; ++j) {
            const int q = min(qb + j, LQ - 1);
            const float4 wv = sT4[q * 101 + (c >> 2)];
            acc[j].x += wv.x * x0.x + wv.y * x1.x + wv.z * x2.x + wv.w * x3.x;
            acc[j].y += wv.x * x0.y + wv.y * x1.y + wv.z * x2.y + wv.w * x3.y;
            acc[j].z += wv.x * x0.z + wv.y * x1.z + wv.z * x2.z + wv.w * x3.z;
            acc[j].w += wv.x * x0.w + wv.y * x1.w + wv.z * x2.w + wv.w * x3.w;
        }
    }
    float4* Tb = (float4*)T + (size_t)b * LQ * 32 + d4;
#pragma unroll
    for (int j = 0; j < 4; ++j) {
        const int q = qb + j;
        if (q < LQ) Tb[q * 32] = acc[j];
    }
}

// ---------------------------------------------------------------------------
// K3: out[b,c,:] = [xc, c2q, xc*c2q, xc*q2c]. Grid (7 c-tiles, B), block 256,
// 2 blocks/CU. Per-thread 8c x 4d (max xv/tv reuse); S_bar tile transposed
// into [q][c] LDS so weights come as 2 broadcast b128 reads per q-iter.
// Epilogue xc rows register-prefetched before the GEMM (HBM latency hidden).
// [round-7 measured 436.6 us]
// ---------------------------------------------------------------------------
#define FMA4(A, s, V) { A.x += (s) * V.x; A.y += (s) * V.y; A.z += (s) * V.z; A.w += (s) * V.w; }

__global__ __launch_bounds__(256, 2) void k_out(
    const float* __restrict__ S_bar, const float* __restrict__ xq_g,
    const float* __restrict__ Tm, const float* __restrict__ xc_g,
    float* __restrict__ out)
{
    __shared__ __align__(16) float xqL[LQ * 132];
    __shared__ __align__(16) float TL[LQ * 132];
    __shared__ __align__(16) float sbT[LQ * 68];   // [q][c-tile], 68 fl = 17x16B

    const int b = blockIdx.y;
    const int c0 = blockIdx.x * CT;
    const int t = threadIdx.x;
    const int nc = min(CT, LC - c0);

    const float4* xq4g = (const float4*)(xq_g + (size_t)b * LQ * D);
    const float4* T4g  = (const float4*)(Tm + (size_t)b * LQ * D);
    for (int i = t; i < LQ * 32; i += 256) {
        const int row = i >> 5, col = i & 31;
        ((float4*)xqL)[row * 33 + col] = xq4g[i];
        ((float4*)TL)[row * 33 + col]  = T4g[i];
    }
    const float* sb_g = S_bar + (size_t)(b * LC + c0) * LQ;
    for (int i = t; i < CT * LQ; i += 256) {
        const int c = i / LQ, q = i - c * LQ;
        sbT[q * 68 + c] = (c < nc) ? sb_g[i] : 0.f;
    }

    const int d4 = t & 31, cg = t >> 5;   // cg 0..7 owns 8 c rows
    const int cbase = cg * 8;

    // prefetch epilogue xc rows (consumed after GEMM; HBM latency hidden)
    const float4* xcv = (const float4*)xc_g;
    float4 xcr[8];
#pragma unroll
    for (int i = 0; i < 8; ++i) {
        int row = b * LC + c0 + cbase + i;
        row = min(row, B * LC - 1);
        xcr[i] = xcv[(size_t)row * 32 + d4];
    }
    __syncthreads();

    float4 c2q[8], q2c[8];
#pragma unroll
    for (int i = 0; i < 8; ++i) {
        c2q[i] = make_float4(0.f, 0.f, 0.f, 0.f);
        q2c[i] = make_float4(0.f, 0.f, 0.f, 0.f);
    }
    const float4* xq4 = (const float4*)xqL;
    const float4* T4  = (const float4*)TL;
    const float4* sb4 = (const float4*)sbT;
    const int cb2 = cg * 2;
    for (int qq = 0; qq < LQ; ++qq) {
        const float4 xv = xq4[qq * 33 + d4];
        const float4 tv = T4[qq * 33 + d4];
        const float4 s0 = sb4[qq * 17 + cb2];
        const float4 s1 = sb4[qq * 17 + cb2 + 1];
        FMA4(c2q[0], s0.x, xv); FMA4(q2c[0], s0.x, tv);
        FMA4(c2q[1], s0.y, xv); FMA4(q2c[1], s0.y, tv);
        FMA4(c2q[2], s0.z, xv); FMA4(q2c[2], s0.z, tv);
        FMA4(c2q[3], s0.w, xv); FMA4(q2c[3], s0.w, tv);
        FMA4(c2q[4], s1.x, xv); FMA4(q2c[4], s1.x, tv);
        FMA4(c2q[5], s1.y, xv); FMA4(q2c[5], s1.y, tv);
        FMA4(c2q[6], s1.z, xv); FMA4(q2c[6], s1.z, tv);
        FMA4(c2q[7], s1.w, xv); FMA4(q2c[7], s1.w, tv);
    }

    float4* out4 = (float4*)out;
#pragma unroll
    for (int i = 0; i < 8; ++i) {
        const int c = cbase + i;
        if (c < nc) {
            const int row = b * LC + c0 + c;
            const float4 xc = xcr[i];
            float4* o = out4 + (size_t)row * 128 + d4;
            o[0] = xc;
            o[32] = c2q[i];
            o[64] = make_float4(xc.x * c2q[i].x, xc.y * c2q[i].y,
                                xc.z * c2q[i].z, xc.w * c2q[i].w);
            o[96] = make_float4(xc.x * q2c[i].x, xc.y * q2c[i].y,
                                xc.z * q2c[i].z, xc.w * q2c[i].w);
        }
    }
}

// ---------------------------------------------------------------------------
extern "C" void kernel_launch(void* const* d_in, const int* in_sizes, int n_in,
                              void* d_out, int out_size, void* d_ws, size_t ws_size,
                              hipStream_t stream)
{
    (void)in_sizes; (void)n_in; (void)out_size; (void)ws_size;
    const float* x_cont = (const float*)d_in[0];
    const float* x_ques = (const float*)d_in[1];
    const float* W0 = (const float*)d_in[2];
    const float* W1 = (const float*)d_in[3];
    const float* W2 = (const float*)d_in[4];
    const int* cont_len = (const int*)d_in[5];
    const int* ques_len = (const int*)d_in[6];

    float* out = (float*)d_out;
    float* out_res  = out;                                  // B*LC*4D
    float* out_Sbar = out + (size_t)B * LC * 4 * D;         // B*LC*LQ
    float* out_ST   = out_Sbar + (size_t)B * LC * LQ;       // B*LQ*LC
    float* Tws = (float*)d_ws;                              // B*LQ*D floats

    k_scores_rowsm<<<dim3(7, B), 256, 0, stream>>>(x_cont, x_ques, W0, W1, W2,
                                                   ques_len, out_Sbar, out_ST);
    k_colsm_qc<<<B, 512, 0, stream>>>(out_ST, x_cont, cont_len, Tws);
    k_out<<<dim3(7, B), 256, 0, stream>>>(out_Sbar, x_ques, Tws, x_cont, out_res);
}